// Round 6
// baseline (867.922 us; speedup 1.0000x reference)
//
#include <hip/hip_runtime.h>
#include <stdint.h>

// ---------------------------------------------------------------------------
// out = x @ nf4_quant_dequant(w).T
//   x: [M=16384, K=4096] fp32,  w: [N=4096, K=4096] fp32,  out: [M, N] fp32
// Plan: (1) ONE fused prep kernel: blocks [0,1024) NF4 fake-quant w -> bf16,
//           blocks [1024,3072) cast x -> bf16 (grid-stride).
//       (2) bf16 MFMA GEMM 256x256/BK=64/8 waves, 8-phase schedule (ROUND-4
//           VERIFIED RING): stages are A-pair/B-pair granular because RDA/RDB
//           are PER-WAVE (wave wn 2,3 read region B.hi at the same phase
//           waves 0,1 read B.lo) -- every region then has stage->first-read
//           distance exactly 5 phases under VMW(8). r4's 1-phase-ahead read
//           pipeline (MFMA consumes fragments read in the previous phase,
//           next reads interleaved mid-cluster, register WAR orders them).
//           T1 XCD swizzle, T2 LDS XOR swizzle, T5 setprio, nt C stores.
// ws usage: w_bf16 (33.5 MB) + x_bf16 (134 MB) = 168 MB.
// ---------------------------------------------------------------------------

typedef __bf16 bf16x8 __attribute__((ext_vector_type(8)));
typedef float f32x4 __attribute__((ext_vector_type(4)));  // native vec

constexpr float NF4_CODE[16] = {
    -1.0f, -0.6961928009986877f, -0.5250730514526367f, -0.39491748809814453f,
    -0.28444138169288635f, -0.18477343022823334f, -0.09105003625154495f, 0.0f,
    0.07958029955625534f, 0.16093020141124725f, 0.24611230194568634f,
    0.33791524171829224f, 0.44070982933044434f, 0.5626170039176941f,
    0.7229568362236023f, 1.0f};
constexpr float NF4_BND[15] = {
    0.5f * (NF4_CODE[0] + NF4_CODE[1]),   0.5f * (NF4_CODE[1] + NF4_CODE[2]),
    0.5f * (NF4_CODE[2] + NF4_CODE[3]),   0.5f * (NF4_CODE[3] + NF4_CODE[4]),
    0.5f * (NF4_CODE[4] + NF4_CODE[5]),   0.5f * (NF4_CODE[5] + NF4_CODE[6]),
    0.5f * (NF4_CODE[6] + NF4_CODE[7]),   0.5f * (NF4_CODE[7] + NF4_CODE[8]),
    0.5f * (NF4_CODE[8] + NF4_CODE[9]),   0.5f * (NF4_CODE[9] + NF4_CODE[10]),
    0.5f * (NF4_CODE[10] + NF4_CODE[11]), 0.5f * (NF4_CODE[11] + NF4_CODE[12]),
    0.5f * (NF4_CODE[12] + NF4_CODE[13]), 0.5f * (NF4_CODE[13] + NF4_CODE[14]),
    0.5f * (NF4_CODE[14] + NF4_CODE[15])};

__device__ __forceinline__ unsigned short f2bf(float f) {
  unsigned int u = __float_as_uint(f);
  u += 0x7fffu + ((u >> 16) & 1u);
  return (unsigned short)(u >> 16);
}

// ---------------------------------------------------------------------------
// Fused prep kernel.
//  blocks [0, nblkW): NF4 fake quant-dequant of w (one scale superblock per
//    block, fully coalesced: round k loads f32x4 idx k*256+t; 16 consecutive
//    lanes own one quant block -> amax via 16-lane shfl_xor reduce).
//  blocks [nblkW, grid): cast x fp32 -> bf16 bits, grid-stride.
// ---------------------------------------------------------------------------
__global__ __launch_bounds__(256) void prep(const float* __restrict__ w,
                                            unsigned short* __restrict__ wdq,
                                            const float* __restrict__ x,
                                            unsigned short* __restrict__ xbf,
                                            int nblkW, size_t n8) {
  __shared__ float s_am[256];
  __shared__ float s_red[4];
  __shared__ float s_code[16];
  const int t = threadIdx.x;

  if ((int)blockIdx.x < nblkW) {
    // ---- NF4 dequant of w ----
    if (t < 16) s_code[t] = NF4_CODE[t];
    const size_t base = (size_t)blockIdx.x * 16384;
    const f32x4* src = (const f32x4*)(w + base);

    f32x4 v[16];
#pragma unroll
    for (int k = 0; k < 16; ++k) {
      v[k] = __builtin_nontemporal_load(src + k * 256 + t);
      float m = fmaxf(fmaxf(fabsf(v[k][0]), fabsf(v[k][1])),
                      fmaxf(fabsf(v[k][2]), fabsf(v[k][3])));
      m = fmaxf(m, __shfl_xor(m, 1));
      m = fmaxf(m, __shfl_xor(m, 2));
      m = fmaxf(m, __shfl_xor(m, 4));
      m = fmaxf(m, __shfl_xor(m, 8));
      if ((t & 15) == 0) s_am[k * 16 + (t >> 4)] = m;  // quant block id
    }
    __syncthreads();
    float m = s_am[t];
    m = fmaxf(m, __shfl_xor(m, 1));
    m = fmaxf(m, __shfl_xor(m, 2));
    m = fmaxf(m, __shfl_xor(m, 4));
    m = fmaxf(m, __shfl_xor(m, 8));
    m = fmaxf(m, __shfl_xor(m, 16));
    m = fmaxf(m, __shfl_xor(m, 32));
    if ((t & 63) == 0) s_red[t >> 6] = m;
    __syncthreads();
    const float s_amax =
        fmaxf(fmaxf(s_red[0], s_red[1]), fmaxf(s_red[2], s_red[3]));
    const float sa = (s_amax == 0.f) ? 1.f : s_amax;

#pragma unroll
    for (int k = 0; k < 16; ++k) {
      const float am = s_am[k * 16 + (t >> 4)];
      float q8 = rintf(am / sa * 127.f);
      q8 = fminf(fmaxf(q8, -127.f), 127.f);
      const float scale = (q8 / 127.f) * sa;
      const float safe_am = (am == 0.f) ? 1.f : am;
      unsigned r[4];
#pragma unroll
      for (int e = 0; e < 4; ++e) {
        const float norm = v[k][e] / safe_am;
        int idx = 0;
#pragma unroll
        for (int j = 0; j < 15; ++j) idx += (NF4_BND[j] < norm) ? 1 : 0;
        r[e] = (unsigned)f2bf(s_code[idx] * scale);
      }
      uint2 o;
      o.x = r[0] | (r[1] << 16);
      o.y = r[2] | (r[3] << 16);
      ((uint2*)(wdq + base))[k * 256 + t] = o;
    }
  } else {
    // ---- cast x -> bf16 ----
    const size_t nth = (size_t)(gridDim.x - nblkW) * 256;
    for (size_t i = (size_t)((int)blockIdx.x - nblkW) * 256 + t; i < n8;
         i += nth) {
      const f32x4* s = (const f32x4*)x + i * 2;
      const f32x4 a = __builtin_nontemporal_load(s);
      const f32x4 b = __builtin_nontemporal_load(s + 1);
      uint4 o;
      o.x = (unsigned)f2bf(a[0]) | ((unsigned)f2bf(a[1]) << 16);
      o.y = (unsigned)f2bf(a[2]) | ((unsigned)f2bf(a[3]) << 16);
      o.z = (unsigned)f2bf(b[0]) | ((unsigned)f2bf(b[1]) << 16);
      o.w = (unsigned)f2bf(b[2]) | ((unsigned)f2bf(b[3]) << 16);
      ((uint4*)xbf)[i] = o;  // xbf IS re-read by the GEMM (L3-resident)
    }
  }
}

// ---------------------------------------------------------------------------
// GEMM: C[M,N] = A[M,K] * Bt[N,K]^T, bf16 in, fp32 out.  (ROUND-4 VERIFIED)
// 256x256 tile, BK=64, 512 thr (8 waves = 2Mx4N, wave = 128x64 via 8x4 of
// 16x16x32 MFMA). 8 phases / 2 K-tiles per iter.
//
// READ PIPELINE (1 phase ahead):
//   P1 MM(0,0)T0 | rd B-hi(T0) |                 (region = per-wave wn/wm!)
//   P2 MM(0,1)T0 | rd A-hi(T0) | stage B(T2) both halves
//   P3 MM(1,0)T0 | rd B-lo(T1) | stage A(T2) both halves
//   P4 MM(1,1)T0 | rd A-lo(T1) |
//   P5 MM(0,0)T1 | rd B-hi(T1) |
//   P6 MM(0,1)T1 | rd A-hi(T1) | stage B(T3) both halves
//   P7 MM(1,0)T1 | rd B-lo(T2) | stage A(T3) both halves
//   P8 MM(1,1)T1 | rd A-lo(T2) |
// Stage->first-read distance is 5 phases for EVERY region (B(T2): P2->P7;
// A(T2): P3->P8; B(T3): P6->P3'; A(T3): P7->P4'), so VMW(8) (= newest 2
// stage-phases may fly) guarantees landing. Ring granularity MUST be
// A-pair/B-pair: RDA/RDB hit region .lo or .hi depending on the WAVE's
// wm/wn, for both mh/nh values (r5 lesson -- finer split races).
// Each phase: { VMW(8); [STG]; barrier; setprio1; MM(ks0); RD(ks0);
//               MM(ks1); RD(ks1); setprio0 } -- MFMA operands were read one
// full phase earlier (ds latency hidden; compiler emits partial lgkm waits);
// RD overwrites exactly the regs the preceding MM consumed (register WAR).
//
// LDS (128 KiB): [buf(2)][A/B(2)][half(2)][128 rows][64 k] bf16, T2 swizzle
// (slot s at row r holds k-chunk s^(r&7); pre-swizzled global source, same
// XOR on ds_read).
// ---------------------------------------------------------------------------

__device__ __forceinline__ void gld16(const unsigned short* g, unsigned short* l) {
  __builtin_amdgcn_global_load_lds(
      (__attribute__((address_space(1))) void*)g,
      (__attribute__((address_space(3))) void*)l, 16, 0, 0);
}

#define BARX                                                                   \
  do {                                                                         \
    asm volatile("" ::: "memory");                                             \
    __builtin_amdgcn_s_barrier();                                              \
    asm volatile("" ::: "memory");                                             \
  } while (0)
#define VMW(n) asm volatile("s_waitcnt vmcnt(" #n ")" ::: "memory")
#define SP1 __builtin_amdgcn_s_setprio(1)
#define SP0 __builtin_amdgcn_s_setprio(0)

#define STG(buf, ab, hf, ks)                                                   \
  do {                                                                         \
    const unsigned short* g_ =                                                 \
        ((ab) ? gB0 : gA0) + (size_t)(hf)*HOFF + (size_t)(ks);                 \
    unsigned short* l_ =                                                       \
        lds + (buf)*32768 + (ab)*16384 + (hf)*8192 + wvoff;                    \
    gld16(g_, l_);                                                             \
    gld16(g_ + 64 * (size_t)K, l_ + 4096);                                     \
  } while (0)

#define RDA(buf, mh, ks)                                                       \
  do {                                                                         \
    _Pragma("unroll") for (int i4 = 0; i4 < 4; ++i4) {                         \
      afr[i4][ks] = *(const bf16x8*)(pa + (buf)*32768 + (mh)*4096 +            \
                                     i4 * 1024 + ((ks) ? aoff1 : aoff0));      \
    }                                                                          \
  } while (0)

#define RDB(buf, nh, ks)                                                       \
  do {                                                                         \
    _Pragma("unroll") for (int j2 = 0; j2 < 2; ++j2) {                         \
      bfr[(nh)*2 + j2][ks] = *(const bf16x8*)(pb + (buf)*32768 + (nh)*2048 +   \
                                              j2 * 1024 +                      \
                                              ((ks) ? aoff1 : aoff0));         \
    }                                                                          \
  } while (0)

#define MMH(mh, nh, ks)                                                        \
  do {                                                                         \
    _Pragma("unroll") for (int i4 = 0; i4 < 4; ++i4) {                         \
      _Pragma("unroll") for (int j2 = 0; j2 < 2; ++j2) {                       \
        acc[(mh)*4 + i4][(nh)*2 + j2] =                                        \
            __builtin_amdgcn_mfma_f32_16x16x32_bf16(                           \
                afr[i4][ks], bfr[(nh)*2 + j2][ks],                             \
                acc[(mh)*4 + i4][(nh)*2 + j2], 0, 0, 0);                       \
      }                                                                        \
    }                                                                          \
  } while (0)

__global__ __launch_bounds__(512, 2) void gemm8p(const unsigned short* __restrict__ A,
                                                 const unsigned short* __restrict__ Bt,
                                                 float* __restrict__ C,
                                                 int M, int N, int K) {
  __shared__ __align__(16) unsigned short lds[65536];  // 128 KiB

  const int t = threadIdx.x;
  const int wave = t >> 6;
  const int lane = t & 63;

  // --- T1: bijective XCD-aware block swizzle ---
  const int nbx = N >> 8;
  const int nwg = nbx * (M >> 8);
  const int q8 = nwg >> 3, r8 = nwg & 7;
  const int xcd = (int)blockIdx.x & 7, off = (int)blockIdx.x >> 3;
  const int wg =
      (xcd < r8 ? xcd * (q8 + 1) : r8 * (q8 + 1) + (xcd - r8) * q8) + off;
  const int bm = (wg / nbx) << 8;
  const int bn = (wg % nbx) << 8;

  // --- staging addressing (per-lane, source pre-swizzled) ---
  const size_t HOFF = (size_t)128 * K;            // half-tile row offset (elems)
  const int srow = wave * 8 + (lane >> 3);        // local row in [0,64)
  const int sj = (lane & 7) ^ (lane >> 3);        // inverse-swizzled k-chunk
  const unsigned short* gA0 = A + (size_t)(bm + srow) * K + sj * 8;
  const unsigned short* gB0 = Bt + (size_t)(bn + srow) * K + sj * 8;
  const int wvoff = wave * 512;                   // LDS chunk base (elems)

  // --- compute addressing ---
  const int wm = wave >> 2;   // m half owned by this wave
  const int wn = wave & 3;    // n quarter owned by this wave
  const int quad = lane >> 4;
  const int lrow = lane & 15;
  const int s0 = quad ^ (lrow & 7);               // swizzled chunk, ks=0
  const int aoff0 = lrow * 64 + s0 * 8;
  const int aoff1 = lrow * 64 + (s0 ^ 4) * 8;     // ks=1
  const unsigned short* pa = lds + wm * 8192;
  const unsigned short* pb = lds + 16384 + (wn >> 1) * 8192 + (wn & 1) * 4096;

  f32x4 acc[8][4];
  const f32x4 zero = {0.f, 0.f, 0.f, 0.f};
#pragma unroll
  for (int i = 0; i < 8; ++i)
#pragma unroll
    for (int j = 0; j < 4; ++j) acc[i][j] = zero;

  bf16x8 afr[4][2];   // current A sub-half (rotates lo->hi->lo' ...)
  bf16x8 bfr[4][2];   // [0..1]=B-lo, [2..3]=B-hi of wave's quarter

  // --- prologue: stage B(T0),A(T0),B(T1),A(T1); prime A-lo/B-lo(T0) ---
  STG(0, 1, 0, 0); STG(0, 1, 1, 0);   // loads 1-4:   B(T0)
  STG(0, 0, 0, 0); STG(0, 0, 1, 0);   // loads 5-8:   A(T0)
  STG(1, 1, 0, 64); STG(1, 1, 1, 64); // loads 9-12:  B(T1)
  STG(1, 0, 0, 64); STG(1, 0, 1, 64); // loads 13-16: A(T1)
  VMW(8);  // B(T0)+A(T0) landed (oldest 8); B(T1)+A(T1) in flight
  BARX;
  RDA(0, 0, 0); RDA(0, 0, 1);  // prime afr = A-lo(T0)
  RDB(0, 0, 0); RDB(0, 0, 1);  // prime bfr[0..1] = B-lo(T0)

  const int niter = K >> 7;  // 2 K-tiles per iteration
  for (int it = 0; it < niter; ++it) {
    const int kt = it << 7;
    int kc2 = kt + 128; if (kc2 > K - 64) kc2 = K - 64;  // T2 (tail: dummy)
    int kc3 = kt + 192; if (kc3 > K - 64) kc3 = K - 64;  // T3 (tail: dummy)

    // P1: MM(lo,lo) T0 | RD B-hi(T0)
    VMW(8); BARX;
    SP1; MMH(0, 0, 0); RDB(0, 1, 0); MMH(0, 0, 1); RDB(0, 1, 1); SP0;
    // P2: MM(lo,hi) T0 | RD A-hi(T0) | stage B(T2)
    VMW(8); STG(0, 1, 0, kc2); STG(0, 1, 1, kc2); BARX;
    SP1; MMH(0, 1, 0); RDA(0, 1, 0); MMH(0, 1, 1); RDA(0, 1, 1); SP0;
    // P3: MM(hi,lo) T0 | RD B-lo(T1) | stage A(T2)
    VMW(8); STG(0, 0, 0, kc2); STG(0, 0, 1, kc2); BARX;
    SP1; MMH(1, 0, 0); RDB(1, 0, 0); MMH(1, 0, 1); RDB(1, 0, 1); SP0;
    // P4: MM(hi,hi) T0 | RD A-lo(T1)
    VMW(8); BARX;
    SP1; MMH(1, 1, 0); RDA(1, 0, 0); MMH(1, 1, 1); RDA(1, 0, 1); SP0;
    // P5: MM(lo,lo) T1 | RD B-hi(T1)
    VMW(8); BARX;
    SP1; MMH(0, 0, 0); RDB(1, 1, 0); MMH(0, 0, 1); RDB(1, 1, 1); SP0;
    // P6: MM(lo,hi) T1 | RD A-hi(T1) | stage B(T3)
    VMW(8); STG(1, 1, 0, kc3); STG(1, 1, 1, kc3); BARX;
    SP1; MMH(0, 1, 0); RDA(1, 1, 0); MMH(0, 1, 1); RDA(1, 1, 1); SP0;
    // P7: MM(hi,lo) T1 | RD B-lo(T2) | stage A(T3)
    VMW(8); STG(1, 0, 0, kc3); STG(1, 0, 1, kc3); BARX;
    SP1; MMH(1, 0, 0); RDB(0, 0, 0); MMH(1, 0, 1); RDB(0, 0, 1); SP0;
    // P8: MM(hi,hi) T1 | RD A-lo(T2)
    VMW(8); BARX;
    SP1; MMH(1, 1, 0); RDA(0, 0, 0); MMH(1, 1, 1); RDA(0, 0, 1); SP0;
  }

  // drain LDS-DMA before epilogue
  VMW(0);

  // epilogue: D[row=quad*4+r][col=lrow] per 16x16 tile; nontemporal stores
  const int crow = bm + wm * 128 + quad * 4;
  const int ccol = bn + wn * 64 + lrow;
#pragma unroll
  for (int i = 0; i < 8; ++i) {
#pragma unroll
    for (int j = 0; j < 4; ++j) {
      float* cp = C + (size_t)(crow + i * 16) * N + (ccol + j * 16);
#pragma unroll
      for (int r = 0; r < 4; ++r)
        __builtin_nontemporal_store(acc[i][j][r], cp + (size_t)r * N);
    }
  }
}

// ---------------------------------------------------------------------------
extern "C" void kernel_launch(void* const* d_in, const int* in_sizes, int n_in,
                              void* d_out, int out_size, void* d_ws, size_t ws_size,
                              hipStream_t stream) {
  const float* x = (const float*)d_in[0];   // [M, K]
  const float* w = (const float*)d_in[1];   // [N, K]
  const int K = 4096;
  const int M = in_sizes[0] / K;            // 16384
  const int N = in_sizes[1] / K;            // 4096

  unsigned short* wdq = (unsigned short*)d_ws;            // [N*K] bf16 bits
  unsigned short* xbf = wdq + (size_t)in_sizes[1];        // [M*K] bf16 bits
  // needs ws_size >= 2*(in_sizes[0]+in_sizes[1]) = 168 MB

  const int nblkW = in_sizes[1] / 16384;    // 1024 dequant blocks
  prep<<<nblkW + 2048, 256, 0, stream>>>(w, wdq, x, xbf, nblkW,
                                         (size_t)in_sizes[0] / 8);
  dim3 grid((N / 256) * (M / 256));
  gemm8p<<<grid, 512, 0, stream>>>(xbf, wdq, (float*)d_out, M, N, K);
}